// Round 5
// baseline (74.551 us; speedup 1.0000x reference)
//
#include <hip/hip_runtime.h>

// R5 = R4 verbatim + ONE duplicate k2 launch (k2 is idempotent).
// Instrumentation round: R5_dur - R4_dur isolates k2's duration, which
// rocprof can't show us (top-5 is all harness fills).

#define C_ 128
#define K_ 64
#define H_ 40
#define W_ 30
#define N_ 4
#define HW_ 1200          // H_*W_
#define P_ 5
#define OH_ 36            // H_+1-P_
#define OW_ 26            // W_+1-P_
#define OHW_ 936

template<int CTRL>
__device__ __forceinline__ float dpp0f(float v) {
  return __int_as_float(__builtin_amdgcn_update_dpp(
      0, __float_as_int(v), CTRL, 0xF, 0xF, true));
}
__device__ __forceinline__ float swz_x16(float v) {
  return __int_as_float(__builtin_amdgcn_ds_swizzle(__float_as_int(v), 0x401F));
}

__global__ __launch_bounds__(256) void k1_prep(
    const float* __restrict__ x, const float* __restrict__ cw,
    float* __restrict__ xn, float* __restrict__ sa)
{
  __shared__ float xs[C_][32];
  __shared__ float wt[C_][K_];
  __shared__ float part[8][32];
  __shared__ float ls[K_][32];
  __shared__ float rnorm_s[32];
  __shared__ float rsum_s[32];

  const int tid  = threadIdx.x;
  const int pix0 = blockIdx.x << 5;

  for (int e = tid; e < C_*K_; e += 256) {
    const int c = e >> 6, kk = e & 63;
    wt[c][kk] = cw[kk*C_ + c];
  }
  for (int e = tid; e < C_*32; e += 256) {
    const int c = e >> 5, pl = e & 31;
    const int pix = pix0 + pl;
    const int n = pix / HW_, rem = pix - n*HW_;
    xs[c][pl] = x[(size_t)(n*C_ + c)*HW_ + rem];
  }
  __syncthreads();
  {
    const int pl = tid & 31, cq = tid >> 5;
    float s = 0.f;
    #pragma unroll
    for (int cc = 0; cc < 16; ++cc) {
      const float v = xs[cq*16 + cc][pl];
      s = fmaf(v, v, s);
    }
    part[cq][pl] = s;
  }
  __syncthreads();
  if (tid < 32) {
    float s = 0.f;
    #pragma unroll
    for (int qq = 0; qq < 8; ++qq) s += part[qq][tid];
    rnorm_s[tid] = 1.f / fmaxf(sqrtf(s), 1e-12f);
  }
  __syncthreads();
  {
    const int pl = tid & 31, kq = tid >> 5;
    float acc[8];
    #pragma unroll
    for (int qq = 0; qq < 8; ++qq) acc[qq] = 0.f;
    for (int c = 0; c < C_; ++c) {
      const float xv = xs[c][pl];
      const float4 w0 = *(const float4*)&wt[c][kq*8];
      const float4 w1 = *(const float4*)&wt[c][kq*8 + 4];
      acc[0] = fmaf(xv, w0.x, acc[0]);
      acc[1] = fmaf(xv, w0.y, acc[1]);
      acc[2] = fmaf(xv, w0.z, acc[2]);
      acc[3] = fmaf(xv, w0.w, acc[3]);
      acc[4] = fmaf(xv, w1.x, acc[4]);
      acc[5] = fmaf(xv, w1.y, acc[5]);
      acc[6] = fmaf(xv, w1.z, acc[6]);
      acc[7] = fmaf(xv, w1.w, acc[7]);
    }
    const float rn = rnorm_s[pl];
    #pragma unroll
    for (int qq = 0; qq < 8; ++qq) ls[kq*8 + qq][pl] = acc[qq] * rn;
  }
  __syncthreads();
  if (tid < 32) {
    const int pl = tid;
    float m = -1e30f;
    for (int kk = 0; kk < K_; ++kk) m = fmaxf(m, ls[kk][pl]);
    float s = 0.f;
    for (int kk = 0; kk < K_; ++kk) {
      const float e = expf(ls[kk][pl] - m);
      ls[kk][pl] = e;
      s += e;
    }
    rsum_s[pl] = 1.f / s;
  }
  __syncthreads();
  for (int e = tid; e < K_*32; e += 256) {
    const int kk = e >> 5, pl = e & 31;
    const int pix = pix0 + pl;
    const int n = pix / HW_, rem = pix - n*HW_;
    sa[(size_t)(n*K_ + kk)*HW_ + rem] = ls[kk][pl] * rsum_s[pl];
  }
  for (int e = tid; e < C_*32; e += 256) {
    const int c = e >> 5, pl = e & 31;
    const int pix = pix0 + pl;
    const int n = pix / HW_, rem = pix - n*HW_;
    xn[(size_t)(n*C_ + c)*HW_ + rem] = xs[c][pl] * rnorm_s[pl];
  }
}

__global__ __launch_bounds__(256, 6) void k2_box(
    const float* __restrict__ xn, const float* __restrict__ sa,
    const float* __restrict__ cent, float* __restrict__ out)
{
  const int tid = threadIdx.x;
  const int w   = tid & 31;
  const int wc  = (w < W_) ? w : (W_ - 1);
  const int c   = (blockIdx.x << 3) + (tid >> 5);
  const int k   = blockIdx.y;
  const int nh  = blockIdx.z;
  const int n   = nh >> 1;
  const int r0  = (nh & 1) * 18;

  const float cv = cent[k*C_ + c];
  const float* __restrict__ xp = xn + (size_t)(n*C_ + c)*HW_ + (size_t)r0*W_ + wc;
  const float* __restrict__ sp = sa + (size_t)(n*K_ + k)*HW_ + (size_t)r0*W_ + wc;

  float q[22];
  #pragma unroll
  for (int h = 0; h < 22; ++h) {
    q[h] = (xp[h*W_] - cv) * sp[h*W_];
  }

  float vq = q[0] + q[1] + q[2] + q[3] + q[4];
  float* __restrict__ op = out + (size_t)((n*K_ + k)*C_ + c)*OHW_
                               + (size_t)r0*OW_ + w;

  #pragma unroll
  for (int i = 0; i < 18; ++i) {
    const float sw = swz_x16(vq);
    float hs = vq;
    hs += dpp0f<0x101>(vq) + dpp0f<0x11F>(sw);
    hs += dpp0f<0x102>(vq) + dpp0f<0x11E>(sw);
    hs += dpp0f<0x103>(vq) + dpp0f<0x11D>(sw);
    hs += dpp0f<0x104>(vq) + dpp0f<0x11C>(sw);
    if (w < OW_) op[i*OW_] = hs * (1.f / (P_*P_));
    if (i < 17) vq += q[i + P_] - q[i];
  }
}

extern "C" void kernel_launch(void* const* d_in, const int* in_sizes, int n_in,
                              void* d_out, int out_size, void* d_ws, size_t ws_size,
                              hipStream_t stream) {
  const float* x  = (const float*)d_in[0];
  const float* cw = (const float*)d_in[1];  // [K,C]
  const float* ce = (const float*)d_in[2];  // [K,C]

  float* xn = (float*)d_ws;
  float* sa = xn + (size_t)N_*C_*HW_;
  float* out = (float*)d_out;

  k1_prep<<<dim3(150), dim3(256), 0, stream>>>(x, cw, xn, sa);
  k2_box<<<dim3(C_/8, K_, N_*2), dim3(256), 0, stream>>>(xn, sa, ce, out);
  // Duplicate launch — idempotent, isolates k2's duration:
  k2_box<<<dim3(C_/8, K_, N_*2), dim3(256), 0, stream>>>(xn, sa, ce, out);
}

// Round 6
// 64.407 us; speedup vs baseline: 1.1575x; 1.1575x over previous
//
#include <hip/hip_runtime.h>

#define C_ 128
#define K_ 64
#define H_ 40
#define W_ 30
#define N_ 4
#define HW_ 1200          // H_*W_
#define P_ 5
#define OH_ 36            // H_+1-P_
#define OW_ 26            // W_+1-P_
#define OHW_ 936

template<int CTRL>
__device__ __forceinline__ float dpp0f(float v) {
  return __int_as_float(__builtin_amdgcn_update_dpp(
      0, __float_as_int(v), CTRL, 0xF, 0xF, true));
}
__device__ __forceinline__ float swz_x16(float v) {
  return __int_as_float(__builtin_amdgcn_ds_swizzle(__float_as_int(v), 0x401F));
}

// ---------------------------------------------------------------------------
// k1a: per-pixel L2 norm + xn write. 75 blocks x 64 threads, thread = pixel.
// Pass 1: 128 coalesced loads, 4 partial sums. Pass 2: L1-hot reload, write xn.
// ---------------------------------------------------------------------------
__global__ __launch_bounds__(64) void k1a_norm(
    const float* __restrict__ x, float* __restrict__ xn,
    float* __restrict__ rnorm)
{
  const int apix = (blockIdx.x << 6) + threadIdx.x;
  const int n   = apix / HW_;
  const int rem = apix - n*HW_;
  const float* __restrict__ xp = x + (size_t)n*C_*HW_ + rem;

  float s0 = 0.f, s1 = 0.f, s2 = 0.f, s3 = 0.f;
  #pragma unroll 8
  for (int c = 0; c < C_; c += 4) {
    const float v0 = xp[(c+0)*HW_];
    const float v1 = xp[(c+1)*HW_];
    const float v2 = xp[(c+2)*HW_];
    const float v3 = xp[(c+3)*HW_];
    s0 = fmaf(v0, v0, s0); s1 = fmaf(v1, v1, s1);
    s2 = fmaf(v2, v2, s2); s3 = fmaf(v3, v3, s3);
  }
  const float rn = 1.f / fmaxf(sqrtf((s0 + s1) + (s2 + s3)), 1e-12f);
  rnorm[apix] = rn;

  float* __restrict__ xo = xn + (size_t)n*C_*HW_ + rem;
  #pragma unroll 8
  for (int c = 0; c < C_; ++c) xo[c*HW_] = xp[c*HW_] * rn;
}

// ---------------------------------------------------------------------------
// k1b: logits[n][k][pix] = rnorm * sum_c cw[k][c]*x[n][c][pix].
// grid (75, 8) x 64 threads; thread = pixel, 8 k's. Weights are wave-uniform
// float4 loads (s_load path, K$-resident). 16-c chunks for ILP.
// ---------------------------------------------------------------------------
__global__ __launch_bounds__(64) void k1b_logits(
    const float* __restrict__ x, const float* __restrict__ cw,
    const float* __restrict__ rnorm, float* __restrict__ logits)
{
  const int apix = (blockIdx.x << 6) + threadIdx.x;
  const int kq   = blockIdx.y;              // 0..7 -> k = kq*8..kq*8+7
  const int n   = apix / HW_;
  const int rem = apix - n*HW_;
  const float* __restrict__ xp = x + (size_t)n*C_*HW_ + rem;

  float acc[8];
  #pragma unroll
  for (int j = 0; j < 8; ++j) acc[j] = 0.f;

  for (int c0 = 0; c0 < C_; c0 += 16) {
    float xv[16];
    #pragma unroll
    for (int j = 0; j < 16; ++j) xv[j] = xp[(c0 + j)*HW_];
    #pragma unroll
    for (int kk = 0; kk < 8; ++kk) {
      const float* __restrict__ wr = cw + (kq*8 + kk)*C_ + c0;
      const float4 w0 = *(const float4*)(wr + 0);
      const float4 w1 = *(const float4*)(wr + 4);
      const float4 w2 = *(const float4*)(wr + 8);
      const float4 w3 = *(const float4*)(wr + 12);
      float a = acc[kk];
      a = fmaf(w0.x, xv[0],  a); a = fmaf(w0.y, xv[1],  a);
      a = fmaf(w0.z, xv[2],  a); a = fmaf(w0.w, xv[3],  a);
      a = fmaf(w1.x, xv[4],  a); a = fmaf(w1.y, xv[5],  a);
      a = fmaf(w1.z, xv[6],  a); a = fmaf(w1.w, xv[7],  a);
      a = fmaf(w2.x, xv[8],  a); a = fmaf(w2.y, xv[9],  a);
      a = fmaf(w2.z, xv[10], a); a = fmaf(w2.w, xv[11], a);
      a = fmaf(w3.x, xv[12], a); a = fmaf(w3.y, xv[13], a);
      a = fmaf(w3.z, xv[14], a); a = fmaf(w3.w, xv[15], a);
      acc[kk] = a;
    }
  }
  const float rn = rnorm[apix];
  float* __restrict__ lp = logits + (size_t)(n*K_ + kq*8)*HW_ + rem;
  #pragma unroll
  for (int kk = 0; kk < 8; ++kk) lp[kk*HW_] = acc[kk] * rn;
}

// ---------------------------------------------------------------------------
// k1c: softmax over K=64 -> sa. 75 blocks x 256 threads.
// Wave wv owns k-slice [wv*16, wv*16+16); lane = pixel. LDS cross-wave reduce.
// ---------------------------------------------------------------------------
__global__ __launch_bounds__(256) void k1c_softmax(
    const float* __restrict__ logits, float* __restrict__ sa)
{
  __shared__ float red[8][64];   // rows 0-3: max, rows 4-7: sum

  const int lane = threadIdx.x & 63;
  const int wv   = threadIdx.x >> 6;
  const int apix = (blockIdx.x << 6) + lane;
  const int n   = apix / HW_;
  const int rem = apix - n*HW_;
  const float* __restrict__ lp = logits + (size_t)(n*K_ + wv*16)*HW_ + rem;

  float v[16];
  #pragma unroll
  for (int j = 0; j < 16; ++j) v[j] = lp[j*HW_];

  float mx = v[0];
  #pragma unroll
  for (int j = 1; j < 16; ++j) mx = fmaxf(mx, v[j]);
  red[wv][lane] = mx;
  __syncthreads();
  mx = fmaxf(fmaxf(red[0][lane], red[1][lane]),
             fmaxf(red[2][lane], red[3][lane]));

  float e[16];
  float sum = 0.f;
  #pragma unroll
  for (int j = 0; j < 16; ++j) { e[j] = expf(v[j] - mx); sum += e[j]; }
  red[4 + wv][lane] = sum;
  __syncthreads();
  const float rs = 1.f / (((red[4][lane] + red[5][lane]) +
                           (red[6][lane] + red[7][lane])));

  float* __restrict__ sp = sa + (size_t)(n*K_ + wv*16)*HW_ + rem;
  #pragma unroll
  for (int j = 0; j < 16; ++j) sp[j*HW_] = e[j] * rs;
}

// ---------------------------------------------------------------------------
// K2: verbatim R4 (measured ~27-28us). Row-split halves, DPP 5-tap.
// ---------------------------------------------------------------------------
__global__ __launch_bounds__(256, 6) void k2_box(
    const float* __restrict__ xn, const float* __restrict__ sa,
    const float* __restrict__ cent, float* __restrict__ out)
{
  const int tid = threadIdx.x;
  const int w   = tid & 31;
  const int wc  = (w < W_) ? w : (W_ - 1);
  const int c   = (blockIdx.x << 3) + (tid >> 5);
  const int k   = blockIdx.y;
  const int nh  = blockIdx.z;
  const int n   = nh >> 1;
  const int r0  = (nh & 1) * 18;

  const float cv = cent[k*C_ + c];
  const float* __restrict__ xp = xn + (size_t)(n*C_ + c)*HW_ + (size_t)r0*W_ + wc;
  const float* __restrict__ sp = sa + (size_t)(n*K_ + k)*HW_ + (size_t)r0*W_ + wc;

  float q[22];
  #pragma unroll
  for (int h = 0; h < 22; ++h) {
    q[h] = (xp[h*W_] - cv) * sp[h*W_];
  }

  float vq = q[0] + q[1] + q[2] + q[3] + q[4];
  float* __restrict__ op = out + (size_t)((n*K_ + k)*C_ + c)*OHW_
                               + (size_t)r0*OW_ + w;

  #pragma unroll
  for (int i = 0; i < 18; ++i) {
    const float sw = swz_x16(vq);
    float hs = vq;
    hs += dpp0f<0x101>(vq) + dpp0f<0x11F>(sw);
    hs += dpp0f<0x102>(vq) + dpp0f<0x11E>(sw);
    hs += dpp0f<0x103>(vq) + dpp0f<0x11D>(sw);
    hs += dpp0f<0x104>(vq) + dpp0f<0x11C>(sw);
    if (w < OW_) op[i*OW_] = hs * (1.f / (P_*P_));
    if (i < 17) vq += q[i + P_] - q[i];
  }
}

extern "C" void kernel_launch(void* const* d_in, const int* in_sizes, int n_in,
                              void* d_out, int out_size, void* d_ws, size_t ws_size,
                              hipStream_t stream) {
  const float* x  = (const float*)d_in[0];
  const float* cw = (const float*)d_in[1];  // [K,C]
  const float* ce = (const float*)d_in[2];  // [K,C]

  float* xn     = (float*)d_ws;                       // 614400 f32
  float* sa     = xn + (size_t)N_*C_*HW_;             // 307200 f32
  float* logits = sa + (size_t)N_*K_*HW_;             // 307200 f32
  float* rnorm  = logits + (size_t)N_*K_*HW_;         // 4800 f32
  float* out = (float*)d_out;

  k1a_norm   <<<dim3(75),     dim3(64),  0, stream>>>(x, xn, rnorm);
  k1b_logits <<<dim3(75, 8),  dim3(64),  0, stream>>>(x, cw, rnorm, logits);
  k1c_softmax<<<dim3(75),     dim3(256), 0, stream>>>(logits, sa);
  k2_box     <<<dim3(C_/8, K_, N_*2), dim3(256), 0, stream>>>(xn, sa, ce, out);
}

// Round 7
// 42.988 us; speedup vs baseline: 1.7342x; 1.4982x over previous
//
#include <hip/hip_runtime.h>

#define C_ 128
#define K_ 64
#define H_ 40
#define W_ 30
#define N_ 4
#define HW_ 1200          // H_*W_
#define P_ 5
#define OH_ 36            // H_+1-P_
#define OW_ 26            // W_+1-P_
#define OHW_ 936
#define PIX_ 16           // pixels per k1 block

template<int CTRL>
__device__ __forceinline__ float dpp0f(float v) {
  return __int_as_float(__builtin_amdgcn_update_dpp(
      0, __float_as_int(v), CTRL, 0xF, 0xF, true));
}
__device__ __forceinline__ float swz_x16(float v) {
  return __int_as_float(__builtin_amdgcn_ds_swizzle(__float_as_int(v), 0x401F));
}

// ---------------------------------------------------------------------------
// K1 v6: fused norm+conv+softmax. 300 blocks x 256 threads, 16 pixels/block.
// xs transposed [pix][c] -> conv xv = 1 ds_read_b128 per 4 c.
// Weights from global (L1/L2-resident float4, near-uniform per wave).
// Thread (pix, kq) computes 4 k's: 1 LDS + 4 VMEM per 16 FMA.
// ---------------------------------------------------------------------------
__global__ __launch_bounds__(256) void k1_fused(
    const float* __restrict__ x, const float* __restrict__ cw,
    float* __restrict__ xn, float* __restrict__ sa)
{
  __shared__ float xs[PIX_][132];     // [pix][c], pad 128->132 (16B rows)
  __shared__ float ls[K_][PIX_ + 2];  // logits/exp [k][pix], pad 18
  __shared__ float red[PIX_][20];     // per-pixel partial reductions
  __shared__ float rnorm_s[PIX_];
  __shared__ float rsum_s[PIX_];

  const int tid = threadIdx.x;
  const int bid = blockIdx.x;
  const int n   = bid / 75;                 // 75 blocks per image
  const int rem = (bid - n*75) * PIX_;      // first pixel in image
  const float* __restrict__ xb = x + (size_t)n*C_*HW_ + rem;

  // ---- stage x -> xs[pix][c] (transpose). thread: c=tid>>2 (+64), 4 pixels
  {
    const int c  = tid >> 2;
    const int p0 = (tid & 3) << 2;
    const float4 v0 = *(const float4*)(xb + (size_t)c*HW_ + p0);
    xs[p0+0][c] = v0.x; xs[p0+1][c] = v0.y;
    xs[p0+2][c] = v0.z; xs[p0+3][c] = v0.w;
    const int c2 = c + 64;
    const float4 v1 = *(const float4*)(xb + (size_t)c2*HW_ + p0);
    xs[p0+0][c2] = v1.x; xs[p0+1][c2] = v1.y;
    xs[p0+2][c2] = v1.z; xs[p0+3][c2] = v1.w;
  }
  __syncthreads();

  // ---- norms: thread (pix=tid&15, cq=tid>>4) sums 8 channels
  {
    const int pix = tid & 15, cq = tid >> 4;
    const float4 a = *(const float4*)&xs[pix][cq*8];
    const float4 b = *(const float4*)&xs[pix][cq*8 + 4];
    red[pix][cq] = (a.x*a.x + a.y*a.y) + (a.z*a.z + a.w*a.w)
                 + (b.x*b.x + b.y*b.y) + (b.z*b.z + b.w*b.w);
  }
  __syncthreads();
  if (tid < PIX_) {
    float s = 0.f;
    #pragma unroll
    for (int j = 0; j < 16; ++j) s += red[tid][j];
    rnorm_s[tid] = 1.f / fmaxf(sqrtf(s), 1e-12f);
  }
  __syncthreads();

  // ---- conv: thread (pix=tid&15, kq=tid>>4) -> k = kq*4..kq*4+3
  {
    const int pix = tid & 15, kq = tid >> 4;
    const float* __restrict__ w0 = cw + (kq*4 + 0)*C_;
    const float* __restrict__ w1 = cw + (kq*4 + 1)*C_;
    const float* __restrict__ w2 = cw + (kq*4 + 2)*C_;
    const float* __restrict__ w3 = cw + (kq*4 + 3)*C_;
    float a0 = 0.f, a1 = 0.f, a2 = 0.f, a3 = 0.f;
    #pragma unroll 8
    for (int c0 = 0; c0 < C_; c0 += 4) {
      const float4 xv = *(const float4*)&xs[pix][c0];
      const float4 wa = *(const float4*)(w0 + c0);
      const float4 wb = *(const float4*)(w1 + c0);
      const float4 wc = *(const float4*)(w2 + c0);
      const float4 wd = *(const float4*)(w3 + c0);
      a0 = fmaf(wa.x, xv.x, a0); a0 = fmaf(wa.y, xv.y, a0);
      a0 = fmaf(wa.z, xv.z, a0); a0 = fmaf(wa.w, xv.w, a0);
      a1 = fmaf(wb.x, xv.x, a1); a1 = fmaf(wb.y, xv.y, a1);
      a1 = fmaf(wb.z, xv.z, a1); a1 = fmaf(wb.w, xv.w, a1);
      a2 = fmaf(wc.x, xv.x, a2); a2 = fmaf(wc.y, xv.y, a2);
      a2 = fmaf(wc.z, xv.z, a2); a2 = fmaf(wc.w, xv.w, a2);
      a3 = fmaf(wd.x, xv.x, a3); a3 = fmaf(wd.y, xv.y, a3);
      a3 = fmaf(wd.z, xv.z, a3); a3 = fmaf(wd.w, xv.w, a3);
    }
    const float rn = rnorm_s[pix];
    ls[kq*4 + 0][pix] = a0 * rn;
    ls[kq*4 + 1][pix] = a1 * rn;
    ls[kq*4 + 2][pix] = a2 * rn;
    ls[kq*4 + 3][pix] = a3 * rn;
  }
  // ---- write xn (reads xs + rnorm_s only; no hazard with ls writes)
  {
    const int c  = tid >> 2;
    const int p0 = (tid & 3) << 2;
    float4 o0, o1;
    o0.x = xs[p0+0][c] * rnorm_s[p0+0];
    o0.y = xs[p0+1][c] * rnorm_s[p0+1];
    o0.z = xs[p0+2][c] * rnorm_s[p0+2];
    o0.w = xs[p0+3][c] * rnorm_s[p0+3];
    *(float4*)(xn + ((size_t)n*C_ + c)*HW_ + rem + p0) = o0;
    const int c2 = c + 64;
    o1.x = xs[p0+0][c2] * rnorm_s[p0+0];
    o1.y = xs[p0+1][c2] * rnorm_s[p0+1];
    o1.z = xs[p0+2][c2] * rnorm_s[p0+2];
    o1.w = xs[p0+3][c2] * rnorm_s[p0+3];
    *(float4*)(xn + ((size_t)n*C_ + c2)*HW_ + rem + p0) = o1;
  }
  __syncthreads();

  // ---- softmax over K=64 per pixel
  {
    const int pix = tid & 15, kq = tid >> 4;
    const float v0 = ls[kq*4 + 0][pix];
    const float v1 = ls[kq*4 + 1][pix];
    const float v2 = ls[kq*4 + 2][pix];
    const float v3 = ls[kq*4 + 3][pix];
    red[pix][kq] = fmaxf(fmaxf(v0, v1), fmaxf(v2, v3));
  }
  __syncthreads();
  if (tid < PIX_) {
    float m = red[tid][0];
    #pragma unroll
    for (int j = 1; j < 16; ++j) m = fmaxf(m, red[tid][j]);
    rnorm_s[tid] = m;     // reuse as row max
  }
  __syncthreads();
  {
    const int pix = tid & 15, kq = tid >> 4;
    const float m = rnorm_s[pix];
    const float e0 = expf(ls[kq*4 + 0][pix] - m);
    const float e1 = expf(ls[kq*4 + 1][pix] - m);
    const float e2 = expf(ls[kq*4 + 2][pix] - m);
    const float e3 = expf(ls[kq*4 + 3][pix] - m);
    ls[kq*4 + 0][pix] = e0;
    ls[kq*4 + 1][pix] = e1;
    ls[kq*4 + 2][pix] = e2;
    ls[kq*4 + 3][pix] = e3;
    red[pix][kq] = (e0 + e1) + (e2 + e3);
  }
  __syncthreads();
  if (tid < PIX_) {
    float s = 0.f;
    #pragma unroll
    for (int j = 0; j < 16; ++j) s += red[tid][j];
    rsum_s[tid] = 1.f / s;
  }
  __syncthreads();
  // ---- write sa: thread (k=tid>>2, 4 pixels), coalesced float4
  {
    const int k  = tid >> 2;
    const int p0 = (tid & 3) << 2;
    float4 o;
    o.x = ls[k][p0+0] * rsum_s[p0+0];
    o.y = ls[k][p0+1] * rsum_s[p0+1];
    o.z = ls[k][p0+2] * rsum_s[p0+2];
    o.w = ls[k][p0+3] * rsum_s[p0+3];
    *(float4*)(sa + ((size_t)n*K_ + k)*HW_ + rem + p0) = o;
  }
}

// ---------------------------------------------------------------------------
// K2: verbatim R4 (measured ~28.5us). Row-split halves, DPP 5-tap.
// ---------------------------------------------------------------------------
__global__ __launch_bounds__(256, 6) void k2_box(
    const float* __restrict__ xn, const float* __restrict__ sa,
    const float* __restrict__ cent, float* __restrict__ out)
{
  const int tid = threadIdx.x;
  const int w   = tid & 31;
  const int wc  = (w < W_) ? w : (W_ - 1);
  const int c   = (blockIdx.x << 3) + (tid >> 5);
  const int k   = blockIdx.y;
  const int nh  = blockIdx.z;
  const int n   = nh >> 1;
  const int r0  = (nh & 1) * 18;

  const float cv = cent[k*C_ + c];
  const float* __restrict__ xp = xn + (size_t)(n*C_ + c)*HW_ + (size_t)r0*W_ + wc;
  const float* __restrict__ sp = sa + (size_t)(n*K_ + k)*HW_ + (size_t)r0*W_ + wc;

  float q[22];
  #pragma unroll
  for (int h = 0; h < 22; ++h) {
    q[h] = (xp[h*W_] - cv) * sp[h*W_];
  }

  float vq = q[0] + q[1] + q[2] + q[3] + q[4];
  float* __restrict__ op = out + (size_t)((n*K_ + k)*C_ + c)*OHW_
                               + (size_t)r0*OW_ + w;

  #pragma unroll
  for (int i = 0; i < 18; ++i) {
    const float sw = swz_x16(vq);
    float hs = vq;
    hs += dpp0f<0x101>(vq) + dpp0f<0x11F>(sw);
    hs += dpp0f<0x102>(vq) + dpp0f<0x11E>(sw);
    hs += dpp0f<0x103>(vq) + dpp0f<0x11D>(sw);
    hs += dpp0f<0x104>(vq) + dpp0f<0x11C>(sw);
    if (w < OW_) op[i*OW_] = hs * (1.f / (P_*P_));
    if (i < 17) vq += q[i + P_] - q[i];
  }
}

extern "C" void kernel_launch(void* const* d_in, const int* in_sizes, int n_in,
                              void* d_out, int out_size, void* d_ws, size_t ws_size,
                              hipStream_t stream) {
  const float* x  = (const float*)d_in[0];
  const float* cw = (const float*)d_in[1];  // [K,C]
  const float* ce = (const float*)d_in[2];  // [K,C]

  float* xn = (float*)d_ws;                 // 4*128*1200 f32
  float* sa = xn + (size_t)N_*C_*HW_;       // 4*64*1200 f32
  float* out = (float*)d_out;

  k1_fused<<<dim3(300), dim3(256), 0, stream>>>(x, cw, xn, sa);
  k2_box  <<<dim3(C_/8, K_, N_*2), dim3(256), 0, stream>>>(xn, sa, ce, out);
}

// Round 8
// 42.352 us; speedup vs baseline: 1.7603x; 1.0150x over previous
//
#include <hip/hip_runtime.h>

#define C_ 128
#define K_ 64
#define H_ 40
#define W_ 30
#define N_ 4
#define HW_ 1200          // H_*W_
#define P_ 5
#define OH_ 36            // H_+1-P_
#define OW_ 26            // W_+1-P_
#define OHW_ 936

template<int CTRL>
__device__ __forceinline__ float dpp0f(float v) {
  return __int_as_float(__builtin_amdgcn_update_dpp(
      0, __float_as_int(v), CTRL, 0xF, 0xF, true));
}
__device__ __forceinline__ float swz_x16(float v) {
  return __int_as_float(__builtin_amdgcn_ds_swizzle(__float_as_int(v), 0x401F));
}

// ---------------------------------------------------------------------------
// K1 v7: fused norm+conv+softmax. 600 blocks x 256 threads, 8 pixels/block
// (~2.3 blocks/CU, 9.4 waves/CU). Thread = (pix, q) computes k=2q,2q+1:
// per 4-c chunk: 1 ds_read_b128 (bank-tiled via pad 132) + 2 global float4
// weight loads (L1-resident, 8-lane shared) + 8 FMA.
// ---------------------------------------------------------------------------
__global__ __launch_bounds__(256) void k1_fused(
    const float* __restrict__ x, const float* __restrict__ cw,
    float* __restrict__ xn, float* __restrict__ sa)
{
  __shared__ float xs[8][132];     // [pix][c], pad 128->132
  __shared__ float ls[8][68];      // [pix][k], pad 64->68
  __shared__ float red[8][36];     // [pix][part] partials
  __shared__ float rnorm_s[8];
  __shared__ float smax_s[8];
  __shared__ float rsum_s[8];

  const int tid = threadIdx.x;
  const int bid = blockIdx.x;
  const int n   = bid / 150;
  const int rem = (bid - n*150) * 8;          // 8 contiguous pixels
  const float* __restrict__ xb = x + (size_t)n*C_*HW_ + rem;

  // ---- stage x -> xs[pix][c]: thread (c=tid>>1, p0=(tid&1)*4), float4
  {
    const int c  = tid >> 1;
    const int p0 = (tid & 1) << 2;
    const float4 v = *(const float4*)(xb + (size_t)c*HW_ + p0);
    xs[p0+0][c] = v.x; xs[p0+1][c] = v.y;
    xs[p0+2][c] = v.z; xs[p0+3][c] = v.w;
  }
  __syncthreads();

  const int pix = tid & 7;
  const int q   = tid >> 3;        // 0..31

  // ---- norm partials: thread (pix, q) sums 4 channels (1 ds_read_b128)
  {
    const float4 v = *(const float4*)&xs[pix][q*4];
    red[pix][q] = (v.x*v.x + v.y*v.y) + (v.z*v.z + v.w*v.w);
  }
  __syncthreads();
  if (tid < 64) {
    const int p = tid >> 3, j = tid & 7;
    float s = ((red[p][j] + red[p][j+8]) + (red[p][j+16] + red[p][j+24]));
    s += __shfl_xor(s, 1, 64); s += __shfl_xor(s, 2, 64); s += __shfl_xor(s, 4, 64);
    if (j == 0) rnorm_s[p] = 1.f / fmaxf(sqrtf(s), 1e-12f);
  }
  __syncthreads();

  // ---- conv: k0=2q, k1=2q+1 for pixel pix
  {
    const float* __restrict__ w0 = cw + (q*2)*C_;
    const float* __restrict__ w1 = w0 + C_;
    float a0 = 0.f, a1 = 0.f;
    #pragma unroll 8
    for (int c0 = 0; c0 < C_; c0 += 4) {
      const float4 xv = *(const float4*)&xs[pix][c0];
      const float4 wa = *(const float4*)(w0 + c0);
      const float4 wb = *(const float4*)(w1 + c0);
      a0 = fmaf(wa.x, xv.x, a0); a0 = fmaf(wa.y, xv.y, a0);
      a0 = fmaf(wa.z, xv.z, a0); a0 = fmaf(wa.w, xv.w, a0);
      a1 = fmaf(wb.x, xv.x, a1); a1 = fmaf(wb.y, xv.y, a1);
      a1 = fmaf(wb.z, xv.z, a1); a1 = fmaf(wb.w, xv.w, a1);
    }
    const float rn = rnorm_s[pix];
    float2 lv; lv.x = a0 * rn; lv.y = a1 * rn;
    *(float2*)&ls[pix][q*2] = lv;
  }

  // ---- write xn (xs + rnorm_s only; independent of ls)
  {
    const int c  = tid >> 1;
    const int p0 = (tid & 1) << 2;
    float4 o;
    o.x = xs[p0+0][c] * rnorm_s[p0+0];
    o.y = xs[p0+1][c] * rnorm_s[p0+1];
    o.z = xs[p0+2][c] * rnorm_s[p0+2];
    o.w = xs[p0+3][c] * rnorm_s[p0+3];
    *(float4*)(xn + ((size_t)n*C_ + c)*HW_ + rem + p0) = o;
  }
  __syncthreads();   // ls ready

  // ---- softmax max: 64 threads, 8 lanes per pixel
  if (tid < 64) {
    const int p = tid >> 3, j = tid & 7;
    const float4 v0 = *(const float4*)&ls[p][j*8];
    const float4 v1 = *(const float4*)&ls[p][j*8 + 4];
    float m = fmaxf(fmaxf(fmaxf(v0.x, v0.y), fmaxf(v0.z, v0.w)),
                    fmaxf(fmaxf(v1.x, v1.y), fmaxf(v1.z, v1.w)));
    m = fmaxf(m, __shfl_xor(m, 1, 64));
    m = fmaxf(m, __shfl_xor(m, 2, 64));
    m = fmaxf(m, __shfl_xor(m, 4, 64));
    if (j == 0) smax_s[p] = m;
  }
  __syncthreads();

  // ---- exp + partial sums
  {
    const float m = smax_s[pix];
    const float2 lv = *(const float2*)&ls[pix][q*2];
    const float e0 = expf(lv.x - m);
    const float e1 = expf(lv.y - m);
    float2 ev; ev.x = e0; ev.y = e1;
    *(float2*)&ls[pix][q*2] = ev;
    red[pix][q] = e0 + e1;
  }
  __syncthreads();
  if (tid < 64) {
    const int p = tid >> 3, j = tid & 7;
    float s = ((red[p][j] + red[p][j+8]) + (red[p][j+16] + red[p][j+24]));
    s += __shfl_xor(s, 1, 64); s += __shfl_xor(s, 2, 64); s += __shfl_xor(s, 4, 64);
    if (j == 0) rsum_s[p] = 1.f / s;
  }
  __syncthreads();

  // ---- write sa: thread (k=tid>>2, ph=(tid&3)*2), float2 over pixels
  {
    const int k  = tid >> 2;
    const int ph = (tid & 3) << 1;
    float2 o;
    o.x = ls[ph + 0][k] * rsum_s[ph + 0];
    o.y = ls[ph + 1][k] * rsum_s[ph + 1];
    *(float2*)(sa + ((size_t)n*K_ + k)*HW_ + rem + ph) = o;
  }
}

// ---------------------------------------------------------------------------
// K2: verbatim R4 (measured ~28.5us). Row-split halves, DPP 5-tap.
// ---------------------------------------------------------------------------
__global__ __launch_bounds__(256, 6) void k2_box(
    const float* __restrict__ xn, const float* __restrict__ sa,
    const float* __restrict__ cent, float* __restrict__ out)
{
  const int tid = threadIdx.x;
  const int w   = tid & 31;
  const int wc  = (w < W_) ? w : (W_ - 1);
  const int c   = (blockIdx.x << 3) + (tid >> 5);
  const int k   = blockIdx.y;
  const int nh  = blockIdx.z;
  const int n   = nh >> 1;
  const int r0  = (nh & 1) * 18;

  const float cv = cent[k*C_ + c];
  const float* __restrict__ xp = xn + (size_t)(n*C_ + c)*HW_ + (size_t)r0*W_ + wc;
  const float* __restrict__ sp = sa + (size_t)(n*K_ + k)*HW_ + (size_t)r0*W_ + wc;

  float q[22];
  #pragma unroll
  for (int h = 0; h < 22; ++h) {
    q[h] = (xp[h*W_] - cv) * sp[h*W_];
  }

  float vq = q[0] + q[1] + q[2] + q[3] + q[4];
  float* __restrict__ op = out + (size_t)((n*K_ + k)*C_ + c)*OHW_
                               + (size_t)r0*OW_ + w;

  #pragma unroll
  for (int i = 0; i < 18; ++i) {
    const float sw = swz_x16(vq);
    float hs = vq;
    hs += dpp0f<0x101>(vq) + dpp0f<0x11F>(sw);
    hs += dpp0f<0x102>(vq) + dpp0f<0x11E>(sw);
    hs += dpp0f<0x103>(vq) + dpp0f<0x11D>(sw);
    hs += dpp0f<0x104>(vq) + dpp0f<0x11C>(sw);
    if (w < OW_) op[i*OW_] = hs * (1.f / (P_*P_));
    if (i < 17) vq += q[i + P_] - q[i];
  }
}

extern "C" void kernel_launch(void* const* d_in, const int* in_sizes, int n_in,
                              void* d_out, int out_size, void* d_ws, size_t ws_size,
                              hipStream_t stream) {
  const float* x  = (const float*)d_in[0];
  const float* cw = (const float*)d_in[1];  // [K,C]
  const float* ce = (const float*)d_in[2];  // [K,C]

  float* xn = (float*)d_ws;                 // 4*128*1200 f32
  float* sa = xn + (size_t)N_*C_*HW_;       // 4*64*1200 f32
  float* out = (float*)d_out;

  k1_fused<<<dim3(600), dim3(256), 0, stream>>>(x, cw, xn, sa);
  k2_box  <<<dim3(C_/8, K_, N_*2), dim3(256), 0, stream>>>(xn, sa, ce, out);
}